// Round 3
// baseline (632.960 us; speedup 1.0000x reference)
//
#include <hip/hip_runtime.h>

typedef unsigned short u16;
typedef unsigned int u32;
typedef __bf16 bf16x8 __attribute__((ext_vector_type(8)));
typedef float f32x4 __attribute__((ext_vector_type(4)));

#define EPS 1e-5f
#define INV_NORM 0.088388347648318447f  // 1/sqrt(128)

// d_out element offsets (fp32 elements)
#define OUT_W   0
#define OUT_LOG 2097152
#define OUT_LP  4194304
#define OUT_S   6291456

// d_ws layout (u16 element offsets)
#define WS_BT   0            // Bt: 16384 x 512 bf16
#define WS_LAT  8388608      // latbf: 512 x 128 bf16 (rows 510/511 garbage, unused)
#define WS_A    8454144      // Abf: 4096 x 512 bf16

__device__ __forceinline__ u16 f2b(float f) {
  u32 i = __float_as_uint(f);
  return (u16)((i + 0x7FFFu + ((i >> 16) & 1u)) >> 16);  // RNE
}
__device__ __forceinline__ float wsum(float v) {
#pragma unroll
  for (int off = 32; off > 0; off >>= 1) v += __shfl_down(v, off, 64);
  return v;
}
__device__ __forceinline__ float wmax(float v) {
#pragma unroll
  for (int off = 32; off > 0; off >>= 1) v = fmaxf(v, __shfl_down(v, off, 64));
  return v;
}
// dot of 8 packed bf16 (uint4) against 8 LDS floats
__device__ __forceinline__ float dot8(uint4 u, const float* xp) {
  float s;
  s  = xp[0] * __uint_as_float(u.x << 16);
  s += xp[1] * __uint_as_float(u.x & 0xFFFF0000u);
  s += xp[2] * __uint_as_float(u.y << 16);
  s += xp[3] * __uint_as_float(u.y & 0xFFFF0000u);
  s += xp[4] * __uint_as_float(u.z << 16);
  s += xp[5] * __uint_as_float(u.z & 0xFFFF0000u);
  s += xp[6] * __uint_as_float(u.w << 16);
  s += xp[7] * __uint_as_float(u.w & 0xFFFF0000u);
  return s;
}
// dot of float4 against 4 LDS floats
__device__ __forceinline__ float dot4(float4 u, const float* xp) {
  return xp[0] * u.x + xp[1] * u.y + xp[2] * u.z + xp[3] * u.w;
}

// ---------------- K1: lat = LN(latents @ linear_w^T + linear_b) -> bf16 ----
__global__ __launch_bounds__(128) void k_lat(const float* __restrict__ latents,
                                             const float* __restrict__ lw,
                                             const float* __restrict__ lb,
                                             u16* __restrict__ latbf) {
  int k = blockIdx.x, t = threadIdx.x;
  int wid = t >> 6, lane = t & 63;
  __shared__ float ls[256];
  __shared__ float red[4];
  ls[t] = latents[k * 256 + t];
  ls[t + 128] = latents[k * 256 + 128 + t];
  __syncthreads();
  float v = lb[t];
  const float4* wv = (const float4*)(lw + t * 256);
#pragma unroll
  for (int c = 0; c < 64; c++) v += dot4(wv[c], &ls[c * 4]);
  float s = wsum(v), s2 = wsum(v * v);
  if (lane == 0) { red[wid * 2] = s; red[wid * 2 + 1] = s2; }
  __syncthreads();
  float mean = (red[0] + red[2]) * 0.0078125f;
  float var = (red[1] + red[3]) * 0.0078125f - mean * mean;
  latbf[k * 128 + t] = f2b((v - mean) * rsqrtf(var + EPS));
}

// ---------------- K2: Bt[n][k] = bf16(sprite[k][n]), n=ch*4096+hw ----------
__global__ __launch_bounds__(256) void k_tr(const float* __restrict__ proto,
                                            const float* __restrict__ masks,
                                            u16* __restrict__ Bt) {
  __shared__ u16 tile[64 * 72];  // [k-local][n-local], pad 72
  int t = threadIdx.x;
  int n0 = blockIdx.x * 64;
  int k0 = blockIdx.y * 64;
  int ch = n0 >> 12, hw0 = n0 & 4095;
  int r = t >> 2, c = (t & 3) * 16;
  int kg = k0 + r;
  u16 vals[16];
#pragma unroll
  for (int e = 0; e < 16; e++) vals[e] = 0;
  if (kg < 510) {
    const float* src = (ch < 3) ? (proto + ((size_t)kg * 3 + ch) * 4096 + hw0 + c)
                                : (masks + (size_t)kg * 4096 + hw0 + c);
    const float4* s4 = (const float4*)src;
#pragma unroll
    for (int q = 0; q < 4; q++) {
      float4 u = s4[q];
      vals[q * 4 + 0] = f2b(u.x);
      vals[q * 4 + 1] = f2b(u.y);
      vals[q * 4 + 2] = f2b(u.z);
      vals[q * 4 + 3] = f2b(u.w);
    }
  }
#pragma unroll
  for (int e = 0; e < 16; e++) tile[r * 72 + c + e] = vals[e];
  __syncthreads();
  int nr = t >> 2, kc = (t & 3) * 16;
  u32 u[8];
#pragma unroll
  for (int e = 0; e < 8; e++) {
    u32 lo = tile[(kc + 2 * e) * 72 + nr];
    u32 hi = tile[(kc + 2 * e + 1) * 72 + nr];
    u[e] = lo | (hi << 16);
  }
  u16* dst = Bt + (size_t)(n0 + nr) * 512 + k0 + kc;
  uint4 v0 = {u[0], u[1], u[2], u[3]};
  uint4 v1 = {u[4], u[5], u[6], u[7]};
  *(uint4*)dst = v0;
  *(uint4*)(dst + 8) = v1;
}

// ---------------- K3: anchors+LN+logits+blank+softmax, 4 rows/block --------
// v2: rows n0..n0+3 (same b, consecutive p) share one block. latbf uint4 and
// aw float4 loads are register-reused across the 4 rows -> latbf L2 traffic
// 512 MB -> 128 MB; x gather becomes coalesced float4. Per-row FP op order
// identical to v1 (same dot4/dot8 sequences), so outputs are bit-identical.
__global__ __launch_bounds__(128) void k_rows(const float* __restrict__ x,
                                              const float* __restrict__ aw,
                                              const float* __restrict__ ab,
                                              const float* __restrict__ blank,
                                              const u16* __restrict__ latbf,
                                              float* __restrict__ out,
                                              u16* __restrict__ Abf) {
  int n0 = blockIdx.x * 4;
  int b = n0 >> 7, p0 = n0 & 127;   // p0 % 4 == 0
  int t = threadIdx.x, wid = t >> 6, lane = t & 63;
  __shared__ float xs[4][128];
  __shared__ float ash[4][128];
  __shared__ float redA[4][6];
  __shared__ float redM[4][2];
  __shared__ float redS[4][2];
  float4 xv = *(const float4*)&x[(size_t)b * 16384 + (size_t)t * 128 + p0];
  xs[0][t] = xv.x; xs[1][t] = xv.y; xs[2][t] = xv.z; xs[3][t] = xv.w;
  __syncthreads();
  float abt = ab[t];
  float av[4];
#pragma unroll
  for (int r = 0; r < 4; r++) av[r] = abt;
  const float4* awv = (const float4*)(aw + t * 128);
#pragma unroll
  for (int c = 0; c < 32; c++) {
    float4 w = awv[c];
#pragma unroll
    for (int r = 0; r < 4; r++) av[r] += dot4(w, &xs[r][c * 4]);
  }
  float bk0 = blank[t], bk1 = blank[128 + t];
#pragma unroll
  for (int r = 0; r < 4; r++) {
    float bv = xs[r][t] * ((r & 1) ? bk1 : bk0);
    float s = wsum(av[r]), s2 = wsum(av[r] * av[r]), sb = wsum(bv);
    if (lane == 0) {
      redA[r][wid * 3] = s; redA[r][wid * 3 + 1] = s2; redA[r][wid * 3 + 2] = sb;
    }
  }
  __syncthreads();
  float bl[4];
#pragma unroll
  for (int r = 0; r < 4; r++) {
    float mean = (redA[r][0] + redA[r][3]) * 0.0078125f;
    float var = (redA[r][1] + redA[r][4]) * 0.0078125f - mean * mean;
    float dots = redA[r][2] + redA[r][5];
    ash[r][t] = (av[r] - mean) * rsqrtf(var + EPS);
    bl[r] = dots * INV_NORM;
  }
  __syncthreads();  // ash visible to all
  // thread t owns k = 4t .. 4t+3; latbf rows loaded once, used for 4 rows
  const uint4* lv = (const uint4*)(latbf + (size_t)(4 * t) * 128);
  float a[4][4];  // [k-sub][row]
#pragma unroll
  for (int kq = 0; kq < 4; kq++)
#pragma unroll
    for (int r = 0; r < 4; r++) a[kq][r] = 0.f;
#pragma unroll
  for (int c = 0; c < 16; c++) {
    uint4 u0 = lv[c], u1 = lv[16 + c], u2 = lv[32 + c], u3 = lv[48 + c];
#pragma unroll
    for (int r = 0; r < 4; r++) {
      const float* ap = &ash[r][c * 8];
      a[0][r] += dot8(u0, ap);
      a[1][r] += dot8(u1, ap);
      a[2][r] += dot8(u2, ap);
      a[3][r] += dot8(u3, ap);
    }
  }
  float l[4][4];  // [row][k-sub]
#pragma unroll
  for (int r = 0; r < 4; r++) {
    l[r][0] = a[0][r] * INV_NORM;
    l[r][1] = a[1][r] * INV_NORM;
    l[r][2] = (4 * t + 2 < 510) ? a[2][r] * INV_NORM : bl[r];  // k=510 -> blank
    l[r][3] = (4 * t + 3 < 510) ? a[3][r] * INV_NORM : bl[r];  // k=511 -> blank
    float lmax = fmaxf(fmaxf(l[r][0], l[r][1]), fmaxf(l[r][2], l[r][3]));
    float m = wmax(lmax);
    if (lane == 0) redM[r][wid] = m;
  }
  __syncthreads();
  float M[4];
#pragma unroll
  for (int r = 0; r < 4; r++) {
    M[r] = fmaxf(redM[r][0], redM[r][1]);
    float se = 0.f;
#pragma unroll
    for (int i = 0; i < 4; i++) se += expf(l[r][i] - M[r]);
    float ssum = wsum(se);
    if (lane == 0) redS[r][wid] = ssum;
  }
  __syncthreads();
#pragma unroll
  for (int r = 0; r < 4; r++) {
    float S = redS[r][0] + redS[r][1];
    float logZ = M[r] + logf(S);
    int n = n0 + r;
    size_t nb = (size_t)n * 512 + 4 * t;
    size_t lpb = (size_t)OUT_LP + ((size_t)(p0 + r) * 32 + b) * 512 + 4 * t;
    float4 wv4, lg4, lp4;
    u16 ab4[4];
    float* lpv = &lp4.x;
    float* wvv = &wv4.x;
    float* lgv = &lg4.x;
#pragma unroll
    for (int i = 0; i < 4; i++) {
      float lp = l[r][i] - logZ;
      float w = expf(lp);
      lpv[i] = lp;
      wvv[i] = w;
      lgv[i] = l[r][i];
      ab4[i] = f2b(w);
    }
    *(float4*)(out + OUT_W + nb) = wv4;
    *(float4*)(out + OUT_LOG + nb) = lg4;
    *(float4*)(out + lpb) = lp4;
    *(uint2*)(Abf + nb) = *(uint2*)ab4;
  }
}

// ---------------- K4: S_out = (weights @ sprite) permuted, bf16 MFMA -------
// v3: 256x256 tile, 8 waves (2M x 4N), BK=64, double-buffered 128 KiB LDS.
// Phase-split pipeline with RAW barriers + counted waits (T3/T4/T5):
//   per kt: {stage half, ds_read kk=0, setprio MFMA x32} x2, then
//   asm vmcnt(0) (own 8 prefetch loads only) + raw s_barrier — no
//   lgkmcnt/expcnt drain, no __syncthreads full-drain.
// Verified XOR k-chunk swizzle (global-side pre-swizzle, linear LDS dest).
// XCD-chunked bijective block swizzle (1024 % 8 == 0).
__global__ __launch_bounds__(512) void k_gemm(const u16* __restrict__ A,
                                              const u16* __restrict__ Bt,
                                              float* __restrict__ out) {
  extern __shared__ u16 lds[];  // [buf=2][ A:256x64 | B:256x64 ] = 131072 B
  int tid = threadIdx.x;
  int wid = tid >> 6, lane = tid & 63;
  int wm = wid >> 2, wn = wid & 3;          // 2 x 4 wave grid; wave tile 128x64
  int quad = lane >> 4, r16 = lane & 15;

  int wg = ((blockIdx.x & 7) << 7) | ((int)blockIdx.x >> 3);
  int mb = wg & 15, nb = wg >> 4;
  int mBase = mb << 8, nBase = nb << 8;

  // staging: thread t covers row q*64 + (t>>3), k-chunk (t&7), global chunk
  // pre-swizzled so LDS chunk c of row r holds global chunk c ^ (r&7).
  int srow = tid >> 3;                       // 0..63
  int kc8 = ((tid & 7) ^ (srow & 7)) << 3;   // swizzled k-offset (elements)
  int sw = r16 & 7;                          // read-side XOR key
  const size_t aRow = (size_t)(mBase + srow) * 512 + kc8;
  const size_t bRow = (size_t)(nBase + srow) * 512 + kc8;

  f32x4 acc[8][4];
#pragma unroll
  for (int i = 0; i < 8; i++)
#pragma unroll
    for (int j = 0; j < 4; j++) acc[i][j] = (f32x4){0.f, 0.f, 0.f, 0.f};

  // one A + one B 16B load for quarter q of K-tile kt into buffer buf
#define STG(buf, kt, q)                                                         \
  do {                                                                          \
    __builtin_amdgcn_global_load_lds(                                           \
        (__attribute__((address_space(1))) void*)(A + aRow +                    \
            (size_t)(q) * 32768 + (kt) * 64),                                   \
        (__attribute__((address_space(3))) void*)((char*)lds +                  \
            (buf) * 65536 + (q) * 8192 + tid * 16), 16, 0, 0);                  \
    __builtin_amdgcn_global_load_lds(                                           \
        (__attribute__((address_space(1))) void*)(Bt + bRow +                   \
            (size_t)(q) * 32768 + (kt) * 64),                                   \
        (__attribute__((address_space(3))) void*)((char*)lds +                  \
            (buf) * 65536 + 32768 + (q) * 8192 + tid * 16), 16, 0, 0);          \
  } while (0)

  // prologue: stage K-tile 0 into buf0, full drain once
  STG(0, 0, 0); STG(0, 0, 1); STG(0, 0, 2); STG(0, 0, 3);
  asm volatile("s_waitcnt vmcnt(0)" ::: "memory");
  __builtin_amdgcn_s_barrier();

#pragma unroll
  for (int kt = 0; kt < 8; ++kt) {
    const int cur = kt & 1;
    const u16* As_ = lds + cur * 32768;      // element offsets (u16)
    const u16* Bs_ = As_ + 16384;
#pragma unroll
    for (int kk = 0; kk < 2; ++kk) {
      // issue half of next tile's staging under this phase's compute
      if (kt < 7) { STG(cur ^ 1, kt + 1, 2 * kk); STG(cur ^ 1, kt + 1, 2 * kk + 1); }
      int ch = ((quad + 4 * kk) ^ sw) << 3;  // de-swizzled LDS chunk (elements)
      bf16x8 bfr[4], af[8];
#pragma unroll
      for (int j = 0; j < 4; j++)
        bfr[j] = *(const bf16x8*)&Bs_[(wn * 64 + j * 16 + r16) * 64 + ch];
#pragma unroll
      for (int i = 0; i < 8; i++)
        af[i] = *(const bf16x8*)&As_[(wm * 128 + i * 16 + r16) * 64 + ch];
      __builtin_amdgcn_s_setprio(1);
#pragma unroll
      for (int i = 0; i < 8; i++)
#pragma unroll
        for (int j = 0; j < 4; j++)
          acc[i][j] = __builtin_amdgcn_mfma_f32_16x16x32_bf16(af[i], bfr[j],
                                                              acc[i][j], 0, 0, 0);
      __builtin_amdgcn_s_setprio(0);
    }
    if (kt < 7) {
      // own 8 prefetch loads are the only outstanding VMEM: counted == 0 here,
      // but NO lgkm/exp drain and no compiler full-drain. Every wave waits its
      // own loads, then barriers -> all waves' staged bytes visible (m152-safe).
      asm volatile("s_waitcnt vmcnt(0)" ::: "memory");
      __builtin_amdgcn_s_barrier();
    }
  }
#undef STG

#pragma unroll
  for (int i = 0; i < 8; i++) {
#pragma unroll
    for (int r = 0; r < 4; r++) {
      int mg = mBase + wm * 128 + i * 16 + quad * 4 + r;
      size_t orow = (size_t)((mg & 127) * 32 + (mg >> 7));  // p*32 + b
      float* orp = out + OUT_S + orow * 16384 + nBase + wn * 64 + r16;
#pragma unroll
      for (int j = 0; j < 4; j++) orp[j * 16] = acc[i][j][r];
    }
  }
}

extern "C" void kernel_launch(void* const* d_in, const int* in_sizes, int n_in,
                              void* d_out, int out_size, void* d_ws, size_t ws_size,
                              hipStream_t stream) {
  const float* x = (const float*)d_in[0];
  const float* latents = (const float*)d_in[1];
  const float* blank = (const float*)d_in[2];
  const float* lw = (const float*)d_in[3];
  const float* lb = (const float*)d_in[4];
  const float* aw = (const float*)d_in[5];
  const float* ab = (const float*)d_in[6];
  const float* proto = (const float*)d_in[7];
  const float* masks = (const float*)d_in[8];
  float* out = (float*)d_out;
  u16* ws16 = (u16*)d_ws;
  u16* Bt = ws16 + WS_BT;
  u16* latbf = ws16 + WS_LAT;
  u16* Abf = ws16 + WS_A;

  k_lat<<<510, 128, 0, stream>>>(latents, lw, lb, latbf);
  k_tr<<<dim3(256, 8), 256, 0, stream>>>(proto, masks, Bt);
  k_rows<<<1024, 128, 0, stream>>>(x, aw, ab, blank, latbf, out, Abf);
  k_gemm<<<1024, 512, 131072, stream>>>(Abf, Bt, out);
}

// Round 4
// 465.323 us; speedup vs baseline: 1.3603x; 1.3603x over previous
//
#include <hip/hip_runtime.h>

typedef unsigned short u16;
typedef unsigned int u32;
typedef __bf16 bf16x8 __attribute__((ext_vector_type(8)));
typedef float f32x4 __attribute__((ext_vector_type(4)));

#define EPS 1e-5f
#define INV_NORM 0.088388347648318447f  // 1/sqrt(128)

// d_out element offsets (fp32 elements)
#define OUT_W   0
#define OUT_LOG 2097152
#define OUT_LP  4194304
#define OUT_S   6291456

// d_ws layout (u16 element offsets)
#define WS_BT   0            // Bt: 16384 x 512 bf16
#define WS_LAT  8388608      // latbf: 512 x 128 bf16 (rows 510/511 garbage, unused)
#define WS_A    8454144      // Abf: 4096 x 512 bf16

__device__ __forceinline__ u16 f2b(float f) {
  u32 i = __float_as_uint(f);
  return (u16)((i + 0x7FFFu + ((i >> 16) & 1u)) >> 16);  // RNE
}
__device__ __forceinline__ float wsum(float v) {
#pragma unroll
  for (int off = 32; off > 0; off >>= 1) v += __shfl_down(v, off, 64);
  return v;
}
__device__ __forceinline__ float wmax(float v) {
#pragma unroll
  for (int off = 32; off > 0; off >>= 1) v = fmaxf(v, __shfl_down(v, off, 64));
  return v;
}
// unpack 8 packed bf16 (uint4) to 8 floats (shifts done ONCE per uint4)
__device__ __forceinline__ void unp8(float* f, uint4 u) {
  f[0] = __uint_as_float(u.x << 16);
  f[1] = __uint_as_float(u.x & 0xFFFF0000u);
  f[2] = __uint_as_float(u.y << 16);
  f[3] = __uint_as_float(u.y & 0xFFFF0000u);
  f[4] = __uint_as_float(u.z << 16);
  f[5] = __uint_as_float(u.z & 0xFFFF0000u);
  f[6] = __uint_as_float(u.w << 16);
  f[7] = __uint_as_float(u.w & 0xFFFF0000u);
}
// dot of 8 unpacked floats against 8 LDS floats — FP order identical to the
// original dot8 (s = x0*f0; s += x1*f1; ...), so results are bit-identical.
__device__ __forceinline__ float dotu(const float* f, const float* xp) {
  float s = xp[0] * f[0];
  s += xp[1] * f[1];
  s += xp[2] * f[2];
  s += xp[3] * f[3];
  s += xp[4] * f[4];
  s += xp[5] * f[5];
  s += xp[6] * f[6];
  s += xp[7] * f[7];
  return s;
}
// dot of float4 against 4 LDS floats
__device__ __forceinline__ float dot4(float4 u, const float* xp) {
  return xp[0] * u.x + xp[1] * u.y + xp[2] * u.z + xp[3] * u.w;
}

// ---------------- K1: lat = LN(latents @ linear_w^T + linear_b) -> bf16 ----
__global__ __launch_bounds__(128) void k_lat(const float* __restrict__ latents,
                                             const float* __restrict__ lw,
                                             const float* __restrict__ lb,
                                             u16* __restrict__ latbf) {
  int k = blockIdx.x, t = threadIdx.x;
  int wid = t >> 6, lane = t & 63;
  __shared__ float ls[256];
  __shared__ float red[4];
  ls[t] = latents[k * 256 + t];
  ls[t + 128] = latents[k * 256 + 128 + t];
  __syncthreads();
  float v = lb[t];
  const float4* wv = (const float4*)(lw + t * 256);
#pragma unroll
  for (int c = 0; c < 64; c++) v += dot4(wv[c], &ls[c * 4]);
  float s = wsum(v), s2 = wsum(v * v);
  if (lane == 0) { red[wid * 2] = s; red[wid * 2 + 1] = s2; }
  __syncthreads();
  float mean = (red[0] + red[2]) * 0.0078125f;
  float var = (red[1] + red[3]) * 0.0078125f - mean * mean;
  latbf[k * 128 + t] = f2b((v - mean) * rsqrtf(var + EPS));
}

// ---------------- K2: Bt[n][k] = bf16(sprite[k][n]), n=ch*4096+hw ----------
__global__ __launch_bounds__(256) void k_tr(const float* __restrict__ proto,
                                            const float* __restrict__ masks,
                                            u16* __restrict__ Bt) {
  __shared__ u16 tile[64 * 72];  // [k-local][n-local], pad 72
  int t = threadIdx.x;
  int n0 = blockIdx.x * 64;
  int k0 = blockIdx.y * 64;
  int ch = n0 >> 12, hw0 = n0 & 4095;
  int r = t >> 2, c = (t & 3) * 16;
  int kg = k0 + r;
  u16 vals[16];
#pragma unroll
  for (int e = 0; e < 16; e++) vals[e] = 0;
  if (kg < 510) {
    const float* src = (ch < 3) ? (proto + ((size_t)kg * 3 + ch) * 4096 + hw0 + c)
                                : (masks + (size_t)kg * 4096 + hw0 + c);
    const float4* s4 = (const float4*)src;
#pragma unroll
    for (int q = 0; q < 4; q++) {
      float4 u = s4[q];
      vals[q * 4 + 0] = f2b(u.x);
      vals[q * 4 + 1] = f2b(u.y);
      vals[q * 4 + 2] = f2b(u.z);
      vals[q * 4 + 3] = f2b(u.w);
    }
  }
#pragma unroll
  for (int e = 0; e < 16; e++) tile[r * 72 + c + e] = vals[e];
  __syncthreads();
  int nr = t >> 2, kc = (t & 3) * 16;
  u32 u[8];
#pragma unroll
  for (int e = 0; e < 8; e++) {
    u32 lo = tile[(kc + 2 * e) * 72 + nr];
    u32 hi = tile[(kc + 2 * e + 1) * 72 + nr];
    u[e] = lo | (hi << 16);
  }
  u16* dst = Bt + (size_t)(n0 + nr) * 512 + k0 + kc;
  uint4 v0 = {u[0], u[1], u[2], u[3]};
  uint4 v1 = {u[4], u[5], u[6], u[7]};
  *(uint4*)dst = v0;
  *(uint4*)(dst + 8) = v1;
}

// ---------------- K3: anchors+LN+logits+blank+softmax, 2 rows/block --------
// v3: rows n0, n0+1 (same b, consecutive even/odd p) share one block.
// latbf uint4 loaded once and UNPACKED ONCE per pair of rows; __launch_bounds__
// (128,4) caps VGPR at 128 to forbid the hoist-balloon/spill that killed the
// 4-row variant (VGPR=256, 2KB/thread scratch). Grid 2048 keeps 16 waves/CU.
// FP op order per output element identical to v1 -> bit-identical results.
__global__ __launch_bounds__(128, 4) void k_rows(const float* __restrict__ x,
                                                 const float* __restrict__ aw,
                                                 const float* __restrict__ ab,
                                                 const float* __restrict__ blank,
                                                 const u16* __restrict__ latbf,
                                                 float* __restrict__ out,
                                                 u16* __restrict__ Abf) {
  int n0 = blockIdx.x * 2;
  int b = n0 >> 7, p0 = n0 & 127;   // p0 even
  int t = threadIdx.x, wid = t >> 6, lane = t & 63;
  __shared__ float xs[2][128];
  __shared__ float ash[2][128];
  __shared__ float redA[2][6];
  __shared__ float redM[2][2];
  __shared__ float redS[2][2];
  float2 xv = *(const float2*)&x[(size_t)b * 16384 + (size_t)t * 128 + p0];
  xs[0][t] = xv.x;
  xs[1][t] = xv.y;
  __syncthreads();
  float abt = ab[t];
  float av0 = abt, av1 = abt;
  const float4* awv = (const float4*)(aw + t * 128);
#pragma unroll
  for (int c = 0; c < 32; c++) {
    float4 w = awv[c];
    av0 += dot4(w, &xs[0][c * 4]);
    av1 += dot4(w, &xs[1][c * 4]);
  }
  {
    float bv0 = xs[0][t] * blank[t];          // p0 even -> blank row 0
    float bv1 = xs[1][t] * blank[128 + t];    // p0+1 odd -> blank row 1
    float s0 = wsum(av0), q0 = wsum(av0 * av0), sb0 = wsum(bv0);
    float s1 = wsum(av1), q1 = wsum(av1 * av1), sb1 = wsum(bv1);
    if (lane == 0) {
      redA[0][wid * 3] = s0; redA[0][wid * 3 + 1] = q0; redA[0][wid * 3 + 2] = sb0;
      redA[1][wid * 3] = s1; redA[1][wid * 3 + 1] = q1; redA[1][wid * 3 + 2] = sb1;
    }
  }
  __syncthreads();
  float bl0, bl1;
  {
    float mean0 = (redA[0][0] + redA[0][3]) * 0.0078125f;
    float var0 = (redA[0][1] + redA[0][4]) * 0.0078125f - mean0 * mean0;
    ash[0][t] = (av0 - mean0) * rsqrtf(var0 + EPS);
    bl0 = (redA[0][2] + redA[0][5]) * INV_NORM;
    float mean1 = (redA[1][0] + redA[1][3]) * 0.0078125f;
    float var1 = (redA[1][1] + redA[1][4]) * 0.0078125f - mean1 * mean1;
    ash[1][t] = (av1 - mean1) * rsqrtf(var1 + EPS);
    bl1 = (redA[1][2] + redA[1][5]) * INV_NORM;
  }
  __syncthreads();  // ash visible to all
  // thread t owns k = 4t .. 4t+3; latbf rows loaded+unpacked once, 2 rows reuse
  const uint4* lv = (const uint4*)(latbf + (size_t)(4 * t) * 128);
  float a00 = 0.f, a10 = 0.f, a20 = 0.f, a30 = 0.f;  // row 0, k-subs 0..3
  float a01 = 0.f, a11 = 0.f, a21 = 0.f, a31 = 0.f;  // row 1
  for (int c = 0; c < 16; c++) {   // no unroll pragma: deny hoist-ballooning
    uint4 u0 = lv[c], u1 = lv[16 + c], u2 = lv[32 + c], u3 = lv[48 + c];
    float f0[8], f1[8], f2[8], f3[8];
    unp8(f0, u0); unp8(f1, u1); unp8(f2, u2); unp8(f3, u3);
    const float* x0 = &ash[0][c * 8];
    const float* x1 = &ash[1][c * 8];
    a00 += dotu(f0, x0); a01 += dotu(f0, x1);
    a10 += dotu(f1, x0); a11 += dotu(f1, x1);
    a20 += dotu(f2, x0); a21 += dotu(f2, x1);
    a30 += dotu(f3, x0); a31 += dotu(f3, x1);
  }
  bool k2ok = (4 * t + 2 < 510), k3ok = (4 * t + 3 < 510);
  float l00 = a00 * INV_NORM, l10 = a10 * INV_NORM;
  float l20 = k2ok ? a20 * INV_NORM : bl0;
  float l30 = k3ok ? a30 * INV_NORM : bl0;
  float l01 = a01 * INV_NORM, l11 = a11 * INV_NORM;
  float l21 = k2ok ? a21 * INV_NORM : bl1;
  float l31 = k3ok ? a31 * INV_NORM : bl1;
  float m0 = wmax(fmaxf(fmaxf(l00, l10), fmaxf(l20, l30)));
  float m1 = wmax(fmaxf(fmaxf(l01, l11), fmaxf(l21, l31)));
  if (lane == 0) { redM[0][wid] = m0; redM[1][wid] = m1; }
  __syncthreads();
  float M0 = fmaxf(redM[0][0], redM[0][1]);
  float M1 = fmaxf(redM[1][0], redM[1][1]);
  float se0 = expf(l00 - M0);
  se0 += expf(l10 - M0); se0 += expf(l20 - M0); se0 += expf(l30 - M0);
  float se1 = expf(l01 - M1);
  se1 += expf(l11 - M1); se1 += expf(l21 - M1); se1 += expf(l31 - M1);
  float ss0 = wsum(se0), ss1 = wsum(se1);
  if (lane == 0) { redS[0][wid] = ss0; redS[1][wid] = ss1; }
  __syncthreads();
  float S0 = redS[0][0] + redS[0][1];
  float S1 = redS[1][0] + redS[1][1];
  float logZ0 = M0 + logf(S0);
  float logZ1 = M1 + logf(S1);
#pragma unroll
  for (int r = 0; r < 2; r++) {
    float lr[4];
    if (r == 0) { lr[0] = l00; lr[1] = l10; lr[2] = l20; lr[3] = l30; }
    else        { lr[0] = l01; lr[1] = l11; lr[2] = l21; lr[3] = l31; }
    float logZ = r ? logZ1 : logZ0;
    int n = n0 + r;
    size_t nb = (size_t)n * 512 + 4 * t;
    size_t lpb = (size_t)OUT_LP + ((size_t)(p0 + r) * 32 + b) * 512 + 4 * t;
    float4 wv4, lg4, lp4;
    u16 ab4[4];
    float* lpv = &lp4.x;
    float* wvv = &wv4.x;
    float* lgv = &lg4.x;
#pragma unroll
    for (int i = 0; i < 4; i++) {
      float lp = lr[i] - logZ;
      float w = expf(lp);
      lpv[i] = lp;
      wvv[i] = w;
      lgv[i] = lr[i];
      ab4[i] = f2b(w);
    }
    *(float4*)(out + OUT_W + nb) = wv4;
    *(float4*)(out + OUT_LOG + nb) = lg4;
    *(float4*)(out + lpb) = lp4;
    *(uint2*)(Abf + nb) = *(uint2*)ab4;
  }
}

// ---------------- K4: S_out = (weights @ sprite) permuted, bf16 MFMA -------
// v3: 256x256 tile, 8 waves (2M x 4N), BK=64, double-buffered 128 KiB LDS.
// Phase-split pipeline with RAW barriers + counted waits (T3/T4/T5).
__global__ __launch_bounds__(512) void k_gemm(const u16* __restrict__ A,
                                              const u16* __restrict__ Bt,
                                              float* __restrict__ out) {
  extern __shared__ u16 lds[];  // [buf=2][ A:256x64 | B:256x64 ] = 131072 B
  int tid = threadIdx.x;
  int wid = tid >> 6, lane = tid & 63;
  int wm = wid >> 2, wn = wid & 3;          // 2 x 4 wave grid; wave tile 128x64
  int quad = lane >> 4, r16 = lane & 15;

  int wg = ((blockIdx.x & 7) << 7) | ((int)blockIdx.x >> 3);
  int mb = wg & 15, nb = wg >> 4;
  int mBase = mb << 8, nBase = nb << 8;

  // staging: thread t covers row q*64 + (t>>3), k-chunk (t&7), global chunk
  // pre-swizzled so LDS chunk c of row r holds global chunk c ^ (r&7).
  int srow = tid >> 3;                       // 0..63
  int kc8 = ((tid & 7) ^ (srow & 7)) << 3;   // swizzled k-offset (elements)
  int sw = r16 & 7;                          // read-side XOR key
  const size_t aRow = (size_t)(mBase + srow) * 512 + kc8;
  const size_t bRow = (size_t)(nBase + srow) * 512 + kc8;

  f32x4 acc[8][4];
#pragma unroll
  for (int i = 0; i < 8; i++)
#pragma unroll
    for (int j = 0; j < 4; j++) acc[i][j] = (f32x4){0.f, 0.f, 0.f, 0.f};

  // one A + one B 16B load for quarter q of K-tile kt into buffer buf
#define STG(buf, kt, q)                                                         \
  do {                                                                          \
    __builtin_amdgcn_global_load_lds(                                           \
        (__attribute__((address_space(1))) void*)(A + aRow +                    \
            (size_t)(q) * 32768 + (kt) * 64),                                   \
        (__attribute__((address_space(3))) void*)((char*)lds +                  \
            (buf) * 65536 + (q) * 8192 + tid * 16), 16, 0, 0);                  \
    __builtin_amdgcn_global_load_lds(                                           \
        (__attribute__((address_space(1))) void*)(Bt + bRow +                   \
            (size_t)(q) * 32768 + (kt) * 64),                                   \
        (__attribute__((address_space(3))) void*)((char*)lds +                  \
            (buf) * 65536 + 32768 + (q) * 8192 + tid * 16), 16, 0, 0);          \
  } while (0)

  // prologue: stage K-tile 0 into buf0, full drain once
  STG(0, 0, 0); STG(0, 0, 1); STG(0, 0, 2); STG(0, 0, 3);
  asm volatile("s_waitcnt vmcnt(0)" ::: "memory");
  __builtin_amdgcn_s_barrier();

#pragma unroll
  for (int kt = 0; kt < 8; ++kt) {
    const int cur = kt & 1;
    const u16* As_ = lds + cur * 32768;      // element offsets (u16)
    const u16* Bs_ = As_ + 16384;
#pragma unroll
    for (int kk = 0; kk < 2; ++kk) {
      // issue half of next tile's staging under this phase's compute
      if (kt < 7) { STG(cur ^ 1, kt + 1, 2 * kk); STG(cur ^ 1, kt + 1, 2 * kk + 1); }
      int ch = ((quad + 4 * kk) ^ sw) << 3;  // de-swizzled LDS chunk (elements)
      bf16x8 bfr[4], af[8];
#pragma unroll
      for (int j = 0; j < 4; j++)
        bfr[j] = *(const bf16x8*)&Bs_[(wn * 64 + j * 16 + r16) * 64 + ch];
#pragma unroll
      for (int i = 0; i < 8; i++)
        af[i] = *(const bf16x8*)&As_[(wm * 128 + i * 16 + r16) * 64 + ch];
      __builtin_amdgcn_s_setprio(1);
#pragma unroll
      for (int i = 0; i < 8; i++)
#pragma unroll
        for (int j = 0; j < 4; j++)
          acc[i][j] = __builtin_amdgcn_mfma_f32_16x16x32_bf16(af[i], bfr[j],
                                                              acc[i][j], 0, 0, 0);
      __builtin_amdgcn_s_setprio(0);
    }
    if (kt < 7) {
      // own 8 prefetch loads are the only outstanding VMEM; every wave waits
      // its own loads, then barriers -> all staged bytes visible (m152-safe).
      asm volatile("s_waitcnt vmcnt(0)" ::: "memory");
      __builtin_amdgcn_s_barrier();
    }
  }
#undef STG

#pragma unroll
  for (int i = 0; i < 8; i++) {
#pragma unroll
    for (int r = 0; r < 4; r++) {
      int mg = mBase + wm * 128 + i * 16 + quad * 4 + r;
      size_t orow = (size_t)((mg & 127) * 32 + (mg >> 7));  // p*32 + b
      float* orp = out + OUT_S + orow * 16384 + nBase + wn * 64 + r16;
#pragma unroll
      for (int j = 0; j < 4; j++) orp[j * 16] = acc[i][j][r];
    }
  }
}

extern "C" void kernel_launch(void* const* d_in, const int* in_sizes, int n_in,
                              void* d_out, int out_size, void* d_ws, size_t ws_size,
                              hipStream_t stream) {
  const float* x = (const float*)d_in[0];
  const float* latents = (const float*)d_in[1];
  const float* blank = (const float*)d_in[2];
  const float* lw = (const float*)d_in[3];
  const float* lb = (const float*)d_in[4];
  const float* aw = (const float*)d_in[5];
  const float* ab = (const float*)d_in[6];
  const float* proto = (const float*)d_in[7];
  const float* masks = (const float*)d_in[8];
  float* out = (float*)d_out;
  u16* ws16 = (u16*)d_ws;
  u16* Bt = ws16 + WS_BT;
  u16* latbf = ws16 + WS_LAT;
  u16* Abf = ws16 + WS_A;

  k_lat<<<510, 128, 0, stream>>>(latents, lw, lb, latbf);
  k_tr<<<dim3(256, 8), 256, 0, stream>>>(proto, masks, Bt);
  k_rows<<<2048, 128, 0, stream>>>(x, aw, ab, blank, latbf, out, Abf);
  k_gemm<<<1024, 512, 131072, stream>>>(Abf, Bt, out);
}

// Round 5
// 431.763 us; speedup vs baseline: 1.4660x; 1.0777x over previous
//
#include <hip/hip_runtime.h>

typedef unsigned short u16;
typedef unsigned int u32;
typedef __bf16 bf16x8 __attribute__((ext_vector_type(8)));
typedef float f32x4 __attribute__((ext_vector_type(4)));

#define EPS 1e-5f
#define INV_NORM 0.088388347648318447f  // 1/sqrt(128)

// d_out element offsets (fp32 elements)
#define OUT_W   0
#define OUT_LOG 2097152
#define OUT_LP  4194304
#define OUT_S   6291456

// d_ws layout (u16 element offsets)
#define WS_BT   0            // Bt: 16384 x 512 bf16
#define WS_LAT  8388608      // latbf: 512 x 128 bf16 (rows 510/511 garbage, unused)
#define WS_A    8454144      // Abf: 4096 x 512 bf16

__device__ __forceinline__ u16 f2b(float f) {
  u32 i = __float_as_uint(f);
  return (u16)((i + 0x7FFFu + ((i >> 16) & 1u)) >> 16);  // RNE
}
__device__ __forceinline__ float wsum(float v) {
#pragma unroll
  for (int off = 32; off > 0; off >>= 1) v += __shfl_down(v, off, 64);
  return v;
}
__device__ __forceinline__ float wmax(float v) {
#pragma unroll
  for (int off = 32; off > 0; off >>= 1) v = fmaxf(v, __shfl_down(v, off, 64));
  return v;
}
// unpack 8 packed bf16 (uint4) to 8 floats (shifts done ONCE per uint4)
__device__ __forceinline__ void unp8(float* f, uint4 u) {
  f[0] = __uint_as_float(u.x << 16);
  f[1] = __uint_as_float(u.x & 0xFFFF0000u);
  f[2] = __uint_as_float(u.y << 16);
  f[3] = __uint_as_float(u.y & 0xFFFF0000u);
  f[4] = __uint_as_float(u.z << 16);
  f[5] = __uint_as_float(u.z & 0xFFFF0000u);
  f[6] = __uint_as_float(u.w << 16);
  f[7] = __uint_as_float(u.w & 0xFFFF0000u);
}
// dot of 8 unpacked floats against 8 LDS floats — FP order identical to the
// original dot8 (s = x0*f0; s += x1*f1; ...), so results are bit-identical.
__device__ __forceinline__ float dotu(const float* f, const float* xp) {
  float s = xp[0] * f[0];
  s += xp[1] * f[1];
  s += xp[2] * f[2];
  s += xp[3] * f[3];
  s += xp[4] * f[4];
  s += xp[5] * f[5];
  s += xp[6] * f[6];
  s += xp[7] * f[7];
  return s;
}
// dot of float4 against 4 LDS floats
__device__ __forceinline__ float dot4(float4 u, const float* xp) {
  return xp[0] * u.x + xp[1] * u.y + xp[2] * u.z + xp[3] * u.w;
}

// ---------------- K1: lat = LN(latents @ linear_w^T + linear_b) -> bf16 ----
__global__ __launch_bounds__(128) void k_lat(const float* __restrict__ latents,
                                             const float* __restrict__ lw,
                                             const float* __restrict__ lb,
                                             u16* __restrict__ latbf) {
  int k = blockIdx.x, t = threadIdx.x;
  int wid = t >> 6, lane = t & 63;
  __shared__ float ls[256];
  __shared__ float red[4];
  ls[t] = latents[k * 256 + t];
  ls[t + 128] = latents[k * 256 + 128 + t];
  __syncthreads();
  float v = lb[t];
  const float4* wv = (const float4*)(lw + t * 256);
#pragma unroll
  for (int c = 0; c < 64; c++) v += dot4(wv[c], &ls[c * 4]);
  float s = wsum(v), s2 = wsum(v * v);
  if (lane == 0) { red[wid * 2] = s; red[wid * 2 + 1] = s2; }
  __syncthreads();
  float mean = (red[0] + red[2]) * 0.0078125f;
  float var = (red[1] + red[3]) * 0.0078125f - mean * mean;
  latbf[k * 128 + t] = f2b((v - mean) * rsqrtf(var + EPS));
}

// ---------------- K2: Bt[n][k] = bf16(sprite[k][n]), n=ch*4096+hw ----------
__global__ __launch_bounds__(256) void k_tr(const float* __restrict__ proto,
                                            const float* __restrict__ masks,
                                            u16* __restrict__ Bt) {
  __shared__ u16 tile[64 * 72];  // [k-local][n-local], pad 72
  int t = threadIdx.x;
  int n0 = blockIdx.x * 64;
  int k0 = blockIdx.y * 64;
  int ch = n0 >> 12, hw0 = n0 & 4095;
  int r = t >> 2, c = (t & 3) * 16;
  int kg = k0 + r;
  u16 vals[16];
#pragma unroll
  for (int e = 0; e < 16; e++) vals[e] = 0;
  if (kg < 510) {
    const float* src = (ch < 3) ? (proto + ((size_t)kg * 3 + ch) * 4096 + hw0 + c)
                                : (masks + (size_t)kg * 4096 + hw0 + c);
    const float4* s4 = (const float4*)src;
#pragma unroll
    for (int q = 0; q < 4; q++) {
      float4 u = s4[q];
      vals[q * 4 + 0] = f2b(u.x);
      vals[q * 4 + 1] = f2b(u.y);
      vals[q * 4 + 2] = f2b(u.z);
      vals[q * 4 + 3] = f2b(u.w);
    }
  }
#pragma unroll
  for (int e = 0; e < 16; e++) tile[r * 72 + c + e] = vals[e];
  __syncthreads();
  int nr = t >> 2, kc = (t & 3) * 16;
  u32 u[8];
#pragma unroll
  for (int e = 0; e < 8; e++) {
    u32 lo = tile[(kc + 2 * e) * 72 + nr];
    u32 hi = tile[(kc + 2 * e + 1) * 72 + nr];
    u[e] = lo | (hi << 16);
  }
  u16* dst = Bt + (size_t)(n0 + nr) * 512 + k0 + kc;
  uint4 v0 = {u[0], u[1], u[2], u[3]};
  uint4 v1 = {u[4], u[5], u[6], u[7]};
  *(uint4*)dst = v0;
  *(uint4*)(dst + 8) = v1;
}

// ---------------- K3: anchors+LN+logits+blank+softmax, 4 rows/block --------
// v4: rows n0..n0+3 (same b, consecutive p, p0%4==0) share one block.
// R3's 4-row variant died from full c-loop unroll (64 hoisted uint4 loads ->
// VGPR 256 + 2KB/thread scratch). This version keeps R4's safe structure:
// unpack-once per uint4, #pragma unroll 1 on the c-loop (forbids ballooning),
// __launch_bounds__(128,4) VGPR cap. latbf L2 traffic 256 MB -> 128 MB.
// FP op order per output element identical to v1 -> bit-identical results.
__global__ __launch_bounds__(128, 4) void k_rows(const float* __restrict__ x,
                                                 const float* __restrict__ aw,
                                                 const float* __restrict__ ab,
                                                 const float* __restrict__ blank,
                                                 const u16* __restrict__ latbf,
                                                 float* __restrict__ out,
                                                 u16* __restrict__ Abf) {
  int n0 = blockIdx.x * 4;
  int b = n0 >> 7, p0 = n0 & 127;   // p0 % 4 == 0
  int t = threadIdx.x, wid = t >> 6, lane = t & 63;
  __shared__ float xs[4][128];
  __shared__ float ash[4][128];
  __shared__ float redA[4][6];
  __shared__ float redM[4][2];
  __shared__ float redS[4][2];
  float4 xv = *(const float4*)&x[(size_t)b * 16384 + (size_t)t * 128 + p0];
  xs[0][t] = xv.x; xs[1][t] = xv.y; xs[2][t] = xv.z; xs[3][t] = xv.w;
  __syncthreads();
  float abt = ab[t];
  float av0 = abt, av1 = abt, av2 = abt, av3 = abt;
  const float4* awv = (const float4*)(aw + t * 128);
#pragma unroll
  for (int c = 0; c < 32; c++) {
    float4 w = awv[c];
    av0 += dot4(w, &xs[0][c * 4]);
    av1 += dot4(w, &xs[1][c * 4]);
    av2 += dot4(w, &xs[2][c * 4]);
    av3 += dot4(w, &xs[3][c * 4]);
  }
  {
    float bk0 = blank[t], bk1 = blank[128 + t];
    float bv0 = xs[0][t] * bk0;   // p0+0 even -> blank row 0
    float bv1 = xs[1][t] * bk1;   // p0+1 odd  -> blank row 1
    float bv2 = xs[2][t] * bk0;
    float bv3 = xs[3][t] * bk1;
    float s0 = wsum(av0), q0 = wsum(av0 * av0), sb0 = wsum(bv0);
    float s1 = wsum(av1), q1 = wsum(av1 * av1), sb1 = wsum(bv1);
    float s2 = wsum(av2), q2 = wsum(av2 * av2), sb2 = wsum(bv2);
    float s3 = wsum(av3), q3 = wsum(av3 * av3), sb3 = wsum(bv3);
    if (lane == 0) {
      redA[0][wid * 3] = s0; redA[0][wid * 3 + 1] = q0; redA[0][wid * 3 + 2] = sb0;
      redA[1][wid * 3] = s1; redA[1][wid * 3 + 1] = q1; redA[1][wid * 3 + 2] = sb1;
      redA[2][wid * 3] = s2; redA[2][wid * 3 + 1] = q2; redA[2][wid * 3 + 2] = sb2;
      redA[3][wid * 3] = s3; redA[3][wid * 3 + 1] = q3; redA[3][wid * 3 + 2] = sb3;
    }
  }
  __syncthreads();
  float bl[4];
  {
    float avr[4] = {av0, av1, av2, av3};
#pragma unroll
    for (int r = 0; r < 4; r++) {
      float mean = (redA[r][0] + redA[r][3]) * 0.0078125f;
      float var = (redA[r][1] + redA[r][4]) * 0.0078125f - mean * mean;
      ash[r][t] = (avr[r] - mean) * rsqrtf(var + EPS);
      bl[r] = (redA[r][2] + redA[r][5]) * INV_NORM;
    }
  }
  __syncthreads();  // ash visible to all
  // thread t owns k = 4t .. 4t+3; latbf rows loaded+unpacked ONCE, 4 rows reuse
  const uint4* lv = (const uint4*)(latbf + (size_t)(4 * t) * 128);
  float a00 = 0.f, a10 = 0.f, a20 = 0.f, a30 = 0.f;  // row 0, k-subs 0..3
  float a01 = 0.f, a11 = 0.f, a21 = 0.f, a31 = 0.f;  // row 1
  float a02 = 0.f, a12 = 0.f, a22 = 0.f, a32 = 0.f;  // row 2
  float a03 = 0.f, a13 = 0.f, a23 = 0.f, a33 = 0.f;  // row 3
#pragma unroll 1
  for (int c = 0; c < 16; c++) {   // unroll FORBIDDEN: deny hoist-ballooning
    uint4 u0 = lv[c], u1 = lv[16 + c], u2 = lv[32 + c], u3 = lv[48 + c];
    float f0[8], f1[8], f2[8], f3[8];
    unp8(f0, u0); unp8(f1, u1); unp8(f2, u2); unp8(f3, u3);
    const float* x0 = &ash[0][c * 8];
    const float* x1 = &ash[1][c * 8];
    const float* x2 = &ash[2][c * 8];
    const float* x3 = &ash[3][c * 8];
    a00 += dotu(f0, x0); a01 += dotu(f0, x1); a02 += dotu(f0, x2); a03 += dotu(f0, x3);
    a10 += dotu(f1, x0); a11 += dotu(f1, x1); a12 += dotu(f1, x2); a13 += dotu(f1, x3);
    a20 += dotu(f2, x0); a21 += dotu(f2, x1); a22 += dotu(f2, x2); a23 += dotu(f2, x3);
    a30 += dotu(f3, x0); a31 += dotu(f3, x1); a32 += dotu(f3, x2); a33 += dotu(f3, x3);
  }
  bool k2ok = (4 * t + 2 < 510), k3ok = (4 * t + 3 < 510);
  float l[4][4];
  l[0][0] = a00 * INV_NORM; l[0][1] = a10 * INV_NORM;
  l[0][2] = k2ok ? a20 * INV_NORM : bl[0];
  l[0][3] = k3ok ? a30 * INV_NORM : bl[0];
  l[1][0] = a01 * INV_NORM; l[1][1] = a11 * INV_NORM;
  l[1][2] = k2ok ? a21 * INV_NORM : bl[1];
  l[1][3] = k3ok ? a31 * INV_NORM : bl[1];
  l[2][0] = a02 * INV_NORM; l[2][1] = a12 * INV_NORM;
  l[2][2] = k2ok ? a22 * INV_NORM : bl[2];
  l[2][3] = k3ok ? a32 * INV_NORM : bl[2];
  l[3][0] = a03 * INV_NORM; l[3][1] = a13 * INV_NORM;
  l[3][2] = k2ok ? a23 * INV_NORM : bl[3];
  l[3][3] = k3ok ? a33 * INV_NORM : bl[3];
#pragma unroll
  for (int r = 0; r < 4; r++) {
    float m = wmax(fmaxf(fmaxf(l[r][0], l[r][1]), fmaxf(l[r][2], l[r][3])));
    if (lane == 0) redM[r][wid] = m;
  }
  __syncthreads();
  float M[4];
#pragma unroll
  for (int r = 0; r < 4; r++) {
    M[r] = fmaxf(redM[r][0], redM[r][1]);
    float se = expf(l[r][0] - M[r]);
    se += expf(l[r][1] - M[r]);
    se += expf(l[r][2] - M[r]);
    se += expf(l[r][3] - M[r]);
    float ss = wsum(se);
    if (lane == 0) redS[r][wid] = ss;
  }
  __syncthreads();
#pragma unroll
  for (int r = 0; r < 4; r++) {
    float S = redS[r][0] + redS[r][1];
    float logZ = M[r] + logf(S);
    int n = n0 + r;
    size_t nb = (size_t)n * 512 + 4 * t;
    size_t lpb = (size_t)OUT_LP + ((size_t)(p0 + r) * 32 + b) * 512 + 4 * t;
    float4 wv4, lg4, lp4;
    u16 ab4[4];
    float* lpv = &lp4.x;
    float* wvv = &wv4.x;
    float* lgv = &lg4.x;
#pragma unroll
    for (int i = 0; i < 4; i++) {
      float lp = l[r][i] - logZ;
      float w = expf(lp);
      lpv[i] = lp;
      wvv[i] = w;
      lgv[i] = l[r][i];
      ab4[i] = f2b(w);
    }
    *(float4*)(out + OUT_W + nb) = wv4;
    *(float4*)(out + OUT_LOG + nb) = lg4;
    *(float4*)(out + lpb) = lp4;
    *(uint2*)(Abf + nb) = *(uint2*)ab4;
  }
}

// ---------------- K4: S_out = (weights @ sprite) permuted, bf16 MFMA -------
// v3: 256x256 tile, 8 waves (2M x 4N), BK=64, double-buffered 128 KiB LDS.
// Phase-split pipeline with RAW barriers + counted waits (T3/T4/T5).
__global__ __launch_bounds__(512) void k_gemm(const u16* __restrict__ A,
                                              const u16* __restrict__ Bt,
                                              float* __restrict__ out) {
  extern __shared__ u16 lds[];  // [buf=2][ A:256x64 | B:256x64 ] = 131072 B
  int tid = threadIdx.x;
  int wid = tid >> 6, lane = tid & 63;
  int wm = wid >> 2, wn = wid & 3;          // 2 x 4 wave grid; wave tile 128x64
  int quad = lane >> 4, r16 = lane & 15;

  int wg = ((blockIdx.x & 7) << 7) | ((int)blockIdx.x >> 3);
  int mb = wg & 15, nb = wg >> 4;
  int mBase = mb << 8, nBase = nb << 8;

  // staging: thread t covers row q*64 + (t>>3), k-chunk (t&7), global chunk
  // pre-swizzled so LDS chunk c of row r holds global chunk c ^ (r&7).
  int srow = tid >> 3;                       // 0..63
  int kc8 = ((tid & 7) ^ (srow & 7)) << 3;   // swizzled k-offset (elements)
  int sw = r16 & 7;                          // read-side XOR key
  const size_t aRow = (size_t)(mBase + srow) * 512 + kc8;
  const size_t bRow = (size_t)(nBase + srow) * 512 + kc8;

  f32x4 acc[8][4];
#pragma unroll
  for (int i = 0; i < 8; i++)
#pragma unroll
    for (int j = 0; j < 4; j++) acc[i][j] = (f32x4){0.f, 0.f, 0.f, 0.f};

  // one A + one B 16B load for quarter q of K-tile kt into buffer buf
#define STG(buf, kt, q)                                                         \
  do {                                                                          \
    __builtin_amdgcn_global_load_lds(                                           \
        (__attribute__((address_space(1))) void*)(A + aRow +                    \
            (size_t)(q) * 32768 + (kt) * 64),                                   \
        (__attribute__((address_space(3))) void*)((char*)lds +                  \
            (buf) * 65536 + (q) * 8192 + tid * 16), 16, 0, 0);                  \
    __builtin_amdgcn_global_load_lds(                                           \
        (__attribute__((address_space(1))) void*)(Bt + bRow +                   \
            (size_t)(q) * 32768 + (kt) * 64),                                   \
        (__attribute__((address_space(3))) void*)((char*)lds +                  \
            (buf) * 65536 + 32768 + (q) * 8192 + tid * 16), 16, 0, 0);          \
  } while (0)

  // prologue: stage K-tile 0 into buf0, full drain once
  STG(0, 0, 0); STG(0, 0, 1); STG(0, 0, 2); STG(0, 0, 3);
  asm volatile("s_waitcnt vmcnt(0)" ::: "memory");
  __builtin_amdgcn_s_barrier();

#pragma unroll
  for (int kt = 0; kt < 8; ++kt) {
    const int cur = kt & 1;
    const u16* As_ = lds + cur * 32768;      // element offsets (u16)
    const u16* Bs_ = As_ + 16384;
#pragma unroll
    for (int kk = 0; kk < 2; ++kk) {
      // issue half of next tile's staging under this phase's compute
      if (kt < 7) { STG(cur ^ 1, kt + 1, 2 * kk); STG(cur ^ 1, kt + 1, 2 * kk + 1); }
      int ch = ((quad + 4 * kk) ^ sw) << 3;  // de-swizzled LDS chunk (elements)
      bf16x8 bfr[4], af[8];
#pragma unroll
      for (int j = 0; j < 4; j++)
        bfr[j] = *(const bf16x8*)&Bs_[(wn * 64 + j * 16 + r16) * 64 + ch];
#pragma unroll
      for (int i = 0; i < 8; i++)
        af[i] = *(const bf16x8*)&As_[(wm * 128 + i * 16 + r16) * 64 + ch];
      __builtin_amdgcn_s_setprio(1);
#pragma unroll
      for (int i = 0; i < 8; i++)
#pragma unroll
        for (int j = 0; j < 4; j++)
          acc[i][j] = __builtin_amdgcn_mfma_f32_16x16x32_bf16(af[i], bfr[j],
                                                              acc[i][j], 0, 0, 0);
      __builtin_amdgcn_s_setprio(0);
    }
    if (kt < 7) {
      // own 8 prefetch loads are the only outstanding VMEM; every wave waits
      // its own loads, then barriers -> all staged bytes visible (m152-safe).
      asm volatile("s_waitcnt vmcnt(0)" ::: "memory");
      __builtin_amdgcn_s_barrier();
    }
  }
#undef STG

#pragma unroll
  for (int i = 0; i < 8; i++) {
#pragma unroll
    for (int r = 0; r < 4; r++) {
      int mg = mBase + wm * 128 + i * 16 + quad * 4 + r;
      size_t orow = (size_t)((mg & 127) * 32 + (mg >> 7));  // p*32 + b
      float* orp = out + OUT_S + orow * 16384 + nBase + wn * 64 + r16;
#pragma unroll
      for (int j = 0; j < 4; j++) orp[j * 16] = acc[i][j][r];
    }
  }
}

extern "C" void kernel_launch(void* const* d_in, const int* in_sizes, int n_in,
                              void* d_out, int out_size, void* d_ws, size_t ws_size,
                              hipStream_t stream) {
  const float* x = (const float*)d_in[0];
  const float* latents = (const float*)d_in[1];
  const float* blank = (const float*)d_in[2];
  const float* lw = (const float*)d_in[3];
  const float* lb = (const float*)d_in[4];
  const float* aw = (const float*)d_in[5];
  const float* ab = (const float*)d_in[6];
  const float* proto = (const float*)d_in[7];
  const float* masks = (const float*)d_in[8];
  float* out = (float*)d_out;
  u16* ws16 = (u16*)d_ws;
  u16* Bt = ws16 + WS_BT;
  u16* latbf = ws16 + WS_LAT;
  u16* Abf = ws16 + WS_A;

  k_lat<<<510, 128, 0, stream>>>(latents, lw, lb, latbf);
  k_tr<<<dim3(256, 8), 256, 0, stream>>>(proto, masks, Bt);
  k_rows<<<1024, 128, 0, stream>>>(x, aw, ab, blank, latbf, out, Abf);
  k_gemm<<<1024, 512, 131072, stream>>>(Abf, Bt, out);
}